// Round 4
// baseline (432.782 us; speedup 1.0000x reference)
//
#include <hip/hip_runtime.h>
#include <math.h>

typedef _Float16 f16;
typedef __attribute__((ext_vector_type(8))) _Float16 half8;
typedef __attribute__((ext_vector_type(4))) float f32x4;

#define NEXP 64
#define TM 64
#define L_STRIDE 132

__device__ __forceinline__ float softplus_f(float x) {
    return fmaxf(x, 0.0f) + log1pf(expf(-fabsf(x)));
}

__device__ __forceinline__ void cvt_split(const float4 a, const float4 b,
                                          half8& hv, half8& lv) {
    const float vv[8] = {a.x, a.y, a.z, a.w, b.x, b.y, b.z, b.w};
#pragma unroll
    for (int j = 0; j < 8; ++j) {
        const f16 h = (f16)vv[j];
        hv[j] = h;
        lv[j] = (f16)((vv[j] - (float)h) * 4096.0f);
    }
}

// ---------------- pre-kernel: split W (route|noise) into f16 hi/lo planes ----
// ws layout (f16 units): [kc][plane(2)][q(4)][col(128)][8]   (16 KB per kc)
__global__ void wsplit_kernel(const float* __restrict__ Wr,
                              const float* __restrict__ Wn,
                              f16* __restrict__ ws, int D) {
    const int per_col = D >> 3;
    const int t = blockIdx.x * blockDim.x + threadIdx.x;
    const int col = t / per_col;
    const int k0  = (t - col * per_col) * 8;
    if (col >= 128) return;
    const float* src = (col < NEXP) ? &Wr[(size_t)col * D] : &Wn[(size_t)(col - NEXP) * D];
    const float4 v0 = *(const float4*)&src[k0];
    const float4 v1 = *(const float4*)&src[k0 + 4];
    half8 hi, lo;
    cvt_split(v0, v1, hi, lo);
    const int kc = k0 >> 5, q = (k0 >> 3) & 3;
    const size_t base = (size_t)kc * 8192 + (size_t)q * 1024 + (size_t)col * 8;
    *(half8*)&ws[base]        = hi;
    *(half8*)&ws[base + 4096] = lo;
}

// ---------------- main kernel: barrier-free K-loop, frags straight from mem --
__global__ __launch_bounds__(256, 3)
void router_mfma_kernel(const float* __restrict__ x,
                        const f16* __restrict__ wsW,
                        const float* __restrict__ br,
                        const float* __restrict__ bn,
                        const float* __restrict__ eps,
                        float* __restrict__ out,
                        int N, int D) {
    __shared__ float L[TM][L_STRIDE];   // 33.8 KB, epilogue only
    __shared__ float biasLDS[128];
    __shared__ float p1s[TM], p2s[TM];
    __shared__ int   i1s[TM], i2s[TM];

    const int tid  = threadIdx.x;
    const int lane = tid & 63;
    const int w    = tid >> 6;
    const int rowbase = blockIdx.x * TM;
    const int wr = w & 1, wc = w >> 1;     // wave tile: 32 rows x 64 cols
    const int quad = lane >> 4;
    const int l16  = lane & 15;

    if (tid < 128) biasLDS[tid] = (tid < NEXP) ? br[tid] : bn[tid - NEXP];

    f32x4 accM[2][4], accC[2][4];
#pragma unroll
    for (int i = 0; i < 2; ++i)
#pragma unroll
        for (int j = 0; j < 4; ++j) {
            accM[i][j] = (f32x4){0.f, 0.f, 0.f, 0.f};
            accC[i][j] = (f32x4){0.f, 0.f, 0.f, 0.f};
        }

    // A: lane (quad,l16) reads x[row = wr*32 + rt*16 + l16][k = kc*32 + quad*8 + 0..7]
    const float* xp0 = &x[(size_t)(rowbase + wr * 32 + l16) * D + quad * 8];
    const float* xp1 = xp0 + (size_t)16 * D;
    // B: frag at wsW + kc*8192 + plane*4096 + quad*1024 + (wc*64 + ct*16 + l16)*8
    const f16* bp0 = wsW + quad * 1024 + (wc * 64 + l16) * 8;   // plane 0 (hi)
    const f16* bp1 = bp0 + 4096;                                 // plane 1 (lo)

    const int nkc = D >> 5;   // 64

    // 1-deep register prefetch of the x stream (the HBM long pole)
    float4 a0n = *(const float4*)(xp0);
    float4 a1n = *(const float4*)(xp0 + 4);
    float4 a2n = *(const float4*)(xp1);
    float4 a3n = *(const float4*)(xp1 + 4);

#pragma unroll 2
    for (int kc = 0; kc < nkc; ++kc) {
        const float4 a0 = a0n, a1 = a1n, a2 = a2n, a3 = a3n;
        if (kc + 1 < nkc) {
            const float* p0 = xp0 + (size_t)(kc + 1) * 32;
            const float* p1 = xp1 + (size_t)(kc + 1) * 32;
            a0n = *(const float4*)(p0);
            a1n = *(const float4*)(p0 + 4);
            a2n = *(const float4*)(p1);
            a3n = *(const float4*)(p1 + 4);
        }

        // B frags straight from L2-resident ws (coalesced 256B runs)
        const f16* b0 = bp0 + (size_t)kc * 8192;
        const f16* b1 = bp1 + (size_t)kc * 8192;
        half8 bh[4], bl[4];
#pragma unroll
        for (int ct = 0; ct < 4; ++ct) {
            bh[ct] = *(const half8*)(b0 + ct * 128);
            bl[ct] = *(const half8*)(b1 + ct * 128);
        }

        // convert this iter's x (loaded a full iter ago) to hi/lo frags
        half8 ah[2], al[2];
        cvt_split(a0, a1, ah[0], al[0]);
        cvt_split(a2, a3, ah[1], al[1]);

#pragma unroll
        for (int rt = 0; rt < 2; ++rt)
#pragma unroll
            for (int ct = 0; ct < 4; ++ct) {
                accM[rt][ct] = __builtin_amdgcn_mfma_f32_16x16x32_f16(ah[rt], bh[ct], accM[rt][ct], 0, 0, 0);
                accC[rt][ct] = __builtin_amdgcn_mfma_f32_16x16x32_f16(al[rt], bh[ct], accC[rt][ct], 0, 0, 0);
                accC[rt][ct] = __builtin_amdgcn_mfma_f32_16x16x32_f16(ah[rt], bl[ct], accC[rt][ct], 0, 0, 0);
            }

        // bound wave drift (keeps wc-pair x reads L1/L2-hot); raw barrier, no waitcnt
        if ((kc & 7) == 7) __builtin_amdgcn_s_barrier();
    }
    __syncthreads();   // biasLDS visibility + align waves for epilogue

    // ---- combine accs + bias -> logits in LDS (C/D: col=lane&15, row=quad*4+reg)
#pragma unroll
    for (int rt = 0; rt < 2; ++rt)
#pragma unroll
        for (int ct = 0; ct < 4; ++ct) {
            const int row = wr * 32 + rt * 16 + quad * 4;
            const int col = wc * 64 + ct * 16 + l16;
            const float bcol = biasLDS[col];
#pragma unroll
            for (int rg = 0; rg < 4; ++rg)
                L[row + rg][col] = accM[rt][ct][rg] + accC[rt][ct][rg] * (1.0f / 4096.0f) + bcol;
        }
    __syncthreads();

    // ---- noisy logits in-place over cols 0..63
#pragma unroll
    for (int t = 0; t < 4; ++t) {
        const int f   = tid * 4 + t * 1024;
        const int row = f >> 6;
        const int e0  = f & 63;
        const float4 ev = *(const float4*)&eps[(size_t)(rowbase + row) * NEXP + e0];
        const float evs[4] = {ev.x, ev.y, ev.z, ev.w};
#pragma unroll
        for (int j = 0; j < 4; ++j) {
            const float lg = L[row][e0 + j];
            const float nz = L[row][NEXP + e0 + j];
            L[row][e0 + j] = fmaf(evs[j], softplus_f(nz), lg);
        }
    }
    __syncthreads();

    // ---- per-row top-2 (strict > = first-occurrence tie-break, matches top_k)
    if (tid < TM) {
        const int r = tid;
        float v1t = -INFINITY, v2t = -INFINITY;
        int i1 = 0, i2 = 0;
#pragma unroll 8
        for (int e = 0; e < NEXP; ++e) {
            const float v = L[r][e];
            if (v > v1t) { v2t = v1t; i2 = i1; v1t = v; i1 = e; }
            else if (v > v2t) { v2t = v; i2 = e; }
        }
        const float z = expf(v2t - v1t);
        const float s = 1.0f + z;
        p1s[r] = 1.0f / s;
        p2s[r] = z / s;
        i1s[r] = i1;
        i2s[r] = i2;
        float* oidx = out + (size_t)N * NEXP + (size_t)(rowbase + r) * 2;
        oidx[0] = (float)i1;
        oidx[1] = (float)i2;
    }
    __syncthreads();

    // ---- sparse-softmax rows, coalesced
    {
        const int r = tid >> 2;
        const int g = tid & 3;
        const float pa = p1s[r], pb = p2s[r];
        const int i1 = i1s[r], i2 = i2s[r];
        float* orow = out + (size_t)(rowbase + r) * NEXP;
#pragma unroll
        for (int t = 0; t < 4; ++t) {
            const int e0 = g * 16 + t * 4;
            float4 o;
            o.x = (e0 + 0 == i1) ? pa : ((e0 + 0 == i2) ? pb : 0.0f);
            o.y = (e0 + 1 == i1) ? pa : ((e0 + 1 == i2) ? pb : 0.0f);
            o.z = (e0 + 2 == i1) ? pa : ((e0 + 2 == i2) ? pb : 0.0f);
            o.w = (e0 + 3 == i1) ? pa : ((e0 + 3 == i2) ? pb : 0.0f);
            *(float4*)&orow[e0] = o;
        }
    }
}

// ---------------- fallback: verified fp32 kernel from R1 ---------------------
#define BK 32
#define XS_STRIDE (TM + 4)
#define WS_STRIDE (128 + 4)

__global__ __launch_bounds__(256, 2)
void noisy_topk_router_kernel(const float* __restrict__ x,
                              const float* __restrict__ Wr,
                              const float* __restrict__ br,
                              const float* __restrict__ Wn,
                              const float* __restrict__ bn,
                              const float* __restrict__ eps,
                              float* __restrict__ out,
                              int N, int D) {
    __shared__ union alignas(16) {
        struct {
            float Xs[BK][XS_STRIDE];
            float Ws[BK][WS_STRIDE];
        } st;
        float L[TM][L_STRIDE];
    } sm;
    __shared__ float p1s[TM], p2s[TM];
    __shared__ int   i1s[TM], i2s[TM];

    const int tid = threadIdx.x;
    const int rowbase = blockIdx.x * TM;
    const int r0 = (tid >> 5) * 8;
    const int c0 = (tid & 31) * 4;

    float acc[8][4];
#pragma unroll
    for (int i = 0; i < 8; ++i)
#pragma unroll
        for (int j = 0; j < 4; ++j) acc[i][j] = 0.0f;

    const int q  = tid & 7;
    const int rr = tid >> 3;

    for (int k0 = 0; k0 < D; k0 += BK) {
#pragma unroll
        for (int i = 0; i < 2; ++i) {
            const int row = rr + 32 * i;
            const float4 xv = *(const float4*)&x[(size_t)(rowbase + row) * D + k0 + q * 4];
            sm.st.Xs[q * 4 + 0][row] = xv.x;
            sm.st.Xs[q * 4 + 1][row] = xv.y;
            sm.st.Xs[q * 4 + 2][row] = xv.z;
            sm.st.Xs[q * 4 + 3][row] = xv.w;
            const float4 wv = *(const float4*)&Wr[(size_t)row * D + k0 + q * 4];
            sm.st.Ws[q * 4 + 0][row] = wv.x;
            sm.st.Ws[q * 4 + 1][row] = wv.y;
            sm.st.Ws[q * 4 + 2][row] = wv.z;
            sm.st.Ws[q * 4 + 3][row] = wv.w;
            const float4 nv = *(const float4*)&Wn[(size_t)row * D + k0 + q * 4];
            sm.st.Ws[q * 4 + 0][NEXP + row] = nv.x;
            sm.st.Ws[q * 4 + 1][NEXP + row] = nv.y;
            sm.st.Ws[q * 4 + 2][NEXP + row] = nv.z;
            sm.st.Ws[q * 4 + 3][NEXP + row] = nv.w;
        }
        __syncthreads();
#pragma unroll 4
        for (int kk = 0; kk < BK; ++kk) {
            const float4 xa = *(const float4*)&sm.st.Xs[kk][r0];
            const float4 xb = *(const float4*)&sm.st.Xs[kk][r0 + 4];
            const float4 wv = *(const float4*)&sm.st.Ws[kk][c0];
            const float xs[8] = {xa.x, xa.y, xa.z, xa.w, xb.x, xb.y, xb.z, xb.w};
            const float ws[4] = {wv.x, wv.y, wv.z, wv.w};
#pragma unroll
            for (int i = 0; i < 8; ++i)
#pragma unroll
                for (int j = 0; j < 4; ++j)
                    acc[i][j] = fmaf(xs[i], ws[j], acc[i][j]);
        }
        __syncthreads();
    }
    {
        const float4 bv = (c0 < NEXP) ? *(const float4*)&br[c0]
                                      : *(const float4*)&bn[c0 - NEXP];
#pragma unroll
        for (int i = 0; i < 8; ++i) {
            float4 o;
            o.x = acc[i][0] + bv.x;
            o.y = acc[i][1] + bv.y;
            o.z = acc[i][2] + bv.z;
            o.w = acc[i][3] + bv.w;
            *(float4*)&sm.L[r0 + i][c0] = o;
        }
    }
    __syncthreads();
#pragma unroll
    for (int t = 0; t < 4; ++t) {
        const int f   = tid * 4 + t * 1024;
        const int row = f >> 6;
        const int e0  = f & 63;
        const float4 ev = *(const float4*)&eps[(size_t)(rowbase + row) * NEXP + e0];
        const float evs[4] = {ev.x, ev.y, ev.z, ev.w};
#pragma unroll
        for (int j = 0; j < 4; ++j) {
            const float lg = sm.L[row][e0 + j];
            const float nz = sm.L[row][NEXP + e0 + j];
            sm.L[row][e0 + j] = fmaf(evs[j], softplus_f(nz), lg);
        }
    }
    __syncthreads();
    if (tid < TM) {
        const int r = tid;
        float v1 = -INFINITY, v2 = -INFINITY;
        int i1 = 0, i2 = 0;
#pragma unroll 8
        for (int e = 0; e < NEXP; ++e) {
            const float v = sm.L[r][e];
            if (v > v1) { v2 = v1; i2 = i1; v1 = v; i1 = e; }
            else if (v > v2) { v2 = v; i2 = e; }
        }
        const float z = expf(v2 - v1);
        const float s = 1.0f + z;
        p1s[r] = 1.0f / s;
        p2s[r] = z / s;
        i1s[r] = i1;
        i2s[r] = i2;
        float* oidx = out + (size_t)N * NEXP + (size_t)(rowbase + r) * 2;
        oidx[0] = (float)i1;
        oidx[1] = (float)i2;
    }
    __syncthreads();
    {
        const int r = tid >> 2;
        const int g = tid & 3;
        const float pa = p1s[r], pb = p2s[r];
        const int i1 = i1s[r], i2 = i2s[r];
        float* orow = out + (size_t)(rowbase + r) * NEXP;
#pragma unroll
        for (int t = 0; t < 4; ++t) {
            const int e0 = g * 16 + t * 4;
            float4 o;
            o.x = (e0 + 0 == i1) ? pa : ((e0 + 0 == i2) ? pb : 0.0f);
            o.y = (e0 + 1 == i1) ? pa : ((e0 + 1 == i2) ? pb : 0.0f);
            o.z = (e0 + 2 == i1) ? pa : ((e0 + 2 == i2) ? pb : 0.0f);
            o.w = (e0 + 3 == i1) ? pa : ((e0 + 3 == i2) ? pb : 0.0f);
            *(float4*)&orow[e0] = o;
        }
    }
}

extern "C" void kernel_launch(void* const* d_in, const int* in_sizes, int n_in,
                              void* d_out, int out_size, void* d_ws, size_t ws_size,
                              hipStream_t stream) {
    const float* x   = (const float*)d_in[0];
    const float* Wr  = (const float*)d_in[1];
    const float* br  = (const float*)d_in[2];
    const float* Wn  = (const float*)d_in[3];
    const float* bn  = (const float*)d_in[4];
    const float* eps = (const float*)d_in[5];
    float* out = (float*)d_out;

    const int E = in_sizes[2];
    const int D = in_sizes[1] / E;
    const int N = in_sizes[0] / D;

    const size_t ws_needed = (size_t)128 * D * 2 * sizeof(f16);
    const bool fast = (E == 64) && (D == 2048) && (N % TM == 0) && (ws_size >= ws_needed);

    if (fast) {
        const int pre_threads = 128 * (D / 8);
        wsplit_kernel<<<(pre_threads + 255) / 256, 256, 0, stream>>>(Wr, Wn, (f16*)d_ws, D);
        router_mfma_kernel<<<N / TM, 256, 0, stream>>>(x, (const f16*)d_ws, br, bn, eps, out, N, D);
    } else {
        noisy_topk_router_kernel<<<N / TM, 256, 0, stream>>>(x, Wr, br, Wn, bn, eps, out, N, D);
    }
}